// Round 11
// baseline (100.794 us; speedup 1.0000x reference)
//
#include <hip/hip_runtime.h>
#include <hip/hip_bf16.h>

typedef __bf16 bf16x8 __attribute__((ext_vector_type(8)));
typedef float f32x4 __attribute__((ext_vector_type(4)));
typedef ushort us8 __attribute__((ext_vector_type(8)));

#define MFMA(a, b, c) __builtin_amdgcn_mfma_f32_16x16x32_bf16((a), (b), (c), 0, 0, 0)

static constexpr int T_LEN = 2048;
static constexpr int C_DIM = 1024;
static constexpr int H_DIM = 128;
static constexpr int M_ROWS = 8 * 2048;    // 16384
static constexpr int N_COLS = 384;         // 3 * 128
static constexpr int SLOTS_PER_B = 528;    // partial slots (qi>=32)
static constexpr int PSTR = 72;            // P buffer row stride
static constexpr int KSTR = 136;           // K LDS row stride (272B, 2-way max)
static constexpr int VSTR = 72;            // V LDS row stride (144B, 2-way max)

__device__ __forceinline__ ushort f2bf(float f) {
  union { float f; unsigned u; } v; v.f = f;
  unsigned u = v.u;
  u += 0x7fffu + ((u >> 16) & 1u);
  return (ushort)(u >> 16);
}
__device__ __forceinline__ float bf2f(ushort u) {
  union { unsigned u; float f; } v; v.u = (unsigned)u << 16;
  return v.f;
}

// raw barrier: lgkmcnt(0) for LDS visibility, NO vmcnt drain (the point).
__device__ __forceinline__ void waitbar() {
  asm volatile("s_waitcnt lgkmcnt(0)" ::: "memory");
  __builtin_amdgcn_s_barrier();
  __builtin_amdgcn_sched_barrier(0);
}

// ---------------------------------------------------------------------------
// Kernel 0: Wq/Wk/Wv fp32 [1024][128] -> bf16 Wt[384][1024] (transposed)
// ---------------------------------------------------------------------------
__global__ void wt_convert(const float* __restrict__ Wq,
                           const float* __restrict__ Wk,
                           const float* __restrict__ Wv,
                           ushort* __restrict__ wt) {
  int flat = blockIdx.x * 256 + threadIdx.x;
  int gc = flat >> 10;
  int c  = flat & 1023;
  int mat = gc >> 7;
  int h   = gc & 127;
  const float* W = (mat == 0) ? Wq : ((mat == 1) ? Wk : Wv);
  wt[flat] = f2bf(W[c * H_DIM + h]);
}

// ---------------------------------------------------------------------------
// Kernel 1: fused QKV projection — raw-barrier pipelined K-loop.
// One raw s_barrier per K-step (double-buffered LDS; tile kt+1 is ds_written
// at step kt from regs loaded at step kt-1, so a single barrier orders both
// the overwrite and the read). Loads issued right after the barrier stay in
// flight across barriers (no compiler vmcnt(0) drain); the dependent cvt /
// MFMA get counted auto-waits. 256 thr, BM=32, BN=192 -> 1024 blocks.
// ---------------------------------------------------------------------------
__global__ __launch_bounds__(256, 4) void qkv_gemm(const float* __restrict__ X,
                                                   const ushort* __restrict__ wt,
                                                   ushort* __restrict__ qws,
                                                   ushort* __restrict__ kws,
                                                   ushort* __restrict__ vtws) {
  __shared__ ushort As[2][32 * 64];
  const int tid = threadIdx.x;
  const int wid = tid >> 6, lane = tid & 63;
  const int lg = lane >> 4, lr = lane & 15;
  const int m0 = (blockIdx.x >> 1) * 32;
  const int n0 = (blockIdx.x & 1) * 192;
  const float QSCL = 0.03125f * 1.44269504f;

  const int srow = tid >> 3;
  const int sbyte = ((tid & 7) * 16) ^ ((srow & 7) << 4);
  const float* xrow = &X[(size_t)(m0 + srow) * C_DIM + (tid & 7) * 8];

  const ushort* wb0 = &wt[(size_t)(n0 + wid * 48 +  0 + lr) * C_DIM + lg * 8];
  const ushort* wb1 = &wt[(size_t)(n0 + wid * 48 + 16 + lr) * C_DIM + lg * 8];
  const ushort* wb2 = &wt[(size_t)(n0 + wid * 48 + 32 + lr) * C_DIM + lg * 8];

  f32x4 acc[2][3];
#pragma unroll
  for (int r = 0; r < 2; ++r)
#pragma unroll
    for (int c = 0; c < 3; ++c)
      acc[r][c] = f32x4{0.f, 0.f, 0.f, 0.f};

  float4 xE0, xE1, xO0, xO1;
  bf16x8 bE[6], bO[6];

  // prologue: tile0 -> xE -> buf0 ; tile1 -> xO (in flight) ; B(tile0) -> bE
  xE0 = *(const float4*)&xrow[0];
  xE1 = *(const float4*)&xrow[4];
  xO0 = *(const float4*)&xrow[64];
  xO1 = *(const float4*)&xrow[64 + 4];
#pragma unroll
  for (int ks = 0; ks < 2; ++ks) {
    bE[0 + ks] = *(const bf16x8*)(wb0 + ks * 32);
    bE[2 + ks] = *(const bf16x8*)(wb1 + ks * 32);
    bE[4 + ks] = *(const bf16x8*)(wb2 + ks * 32);
  }
  {
    us8 bv;
    bv[0] = f2bf(xE0.x); bv[1] = f2bf(xE0.y); bv[2] = f2bf(xE0.z); bv[3] = f2bf(xE0.w);
    bv[4] = f2bf(xE1.x); bv[5] = f2bf(xE1.y); bv[6] = f2bf(xE1.z); bv[7] = f2bf(xE1.w);
    *(us8*)((char*)&As[0][0] + srow * 128 + sbyte) = bv;
  }

  for (int k2 = 0; k2 < 16; k2 += 2) {
    // ---- even step kt = k2: read buf0 (tile k2), consume bE ----
    waitbar();                       // buf0 (tile k2) visible; buf1 free
    if (k2 + 2 < 16) {               // issue X(tile k2+2) early (stays in flight)
      xE0 = *(const float4*)&xrow[(k2 + 2) * 64];
      xE1 = *(const float4*)&xrow[(k2 + 2) * 64 + 4];
    }
    if (k2 + 1 < 16) {               // issue B(tile k2+1) early
#pragma unroll
      for (int ks = 0; ks < 2; ++ks) {
        bO[0 + ks] = *(const bf16x8*)(wb0 + (k2 + 1) * 64 + ks * 32);
        bO[2 + ks] = *(const bf16x8*)(wb1 + (k2 + 1) * 64 + ks * 32);
        bO[4 + ks] = *(const bf16x8*)(wb2 + (k2 + 1) * 64 + ks * 32);
      }
      // stage tile k2+1 (xO loaded one step ago) into buf1
      us8 bv;
      bv[0] = f2bf(xO0.x); bv[1] = f2bf(xO0.y); bv[2] = f2bf(xO0.z); bv[3] = f2bf(xO0.w);
      bv[4] = f2bf(xO1.x); bv[5] = f2bf(xO1.y); bv[6] = f2bf(xO1.z); bv[7] = f2bf(xO1.w);
      *(us8*)((char*)&As[1][0] + srow * 128 + sbyte) = bv;
    }
    {
      bf16x8 a[2][2];
#pragma unroll
      for (int r = 0; r < 2; ++r)
#pragma unroll
        for (int ks = 0; ks < 2; ++ks) {
          int row = r * 16 + lr;
          int cb = (ks * 64 + lg * 16) ^ ((row & 7) << 4);
          a[r][ks] = *(const bf16x8*)((const char*)&As[0][0] + row * 128 + cb);
        }
#pragma unroll
      for (int c = 0; c < 3; ++c)
#pragma unroll
        for (int ks = 0; ks < 2; ++ks) {
          acc[0][c] = MFMA(a[0][ks], bE[c * 2 + ks], acc[0][c]);
          acc[1][c] = MFMA(a[1][ks], bE[c * 2 + ks], acc[1][c]);
        }
    }

    // ---- odd step kt = k2+1: read buf1 (tile k2+1), consume bO ----
    waitbar();                       // buf1 (tile k2+1) visible; buf0 free
    if (k2 + 3 < 16) {
      xO0 = *(const float4*)&xrow[(k2 + 3) * 64];
      xO1 = *(const float4*)&xrow[(k2 + 3) * 64 + 4];
    }
    if (k2 + 2 < 16) {
#pragma unroll
      for (int ks = 0; ks < 2; ++ks) {
        bE[0 + ks] = *(const bf16x8*)(wb0 + (k2 + 2) * 64 + ks * 32);
        bE[2 + ks] = *(const bf16x8*)(wb1 + (k2 + 2) * 64 + ks * 32);
        bE[4 + ks] = *(const bf16x8*)(wb2 + (k2 + 2) * 64 + ks * 32);
      }
      // stage tile k2+2 (xE loaded in even step) into buf0
      us8 bv;
      bv[0] = f2bf(xE0.x); bv[1] = f2bf(xE0.y); bv[2] = f2bf(xE0.z); bv[3] = f2bf(xE0.w);
      bv[4] = f2bf(xE1.x); bv[5] = f2bf(xE1.y); bv[6] = f2bf(xE1.z); bv[7] = f2bf(xE1.w);
      *(us8*)((char*)&As[0][0] + srow * 128 + sbyte) = bv;
    }
    {
      bf16x8 a[2][2];
#pragma unroll
      for (int r = 0; r < 2; ++r)
#pragma unroll
        for (int ks = 0; ks < 2; ++ks) {
          int row = r * 16 + lr;
          int cb = (ks * 64 + lg * 16) ^ ((row & 7) << 4);
          a[r][ks] = *(const bf16x8*)((const char*)&As[1][0] + row * 128 + cb);
        }
#pragma unroll
      for (int c = 0; c < 3; ++c)
#pragma unroll
        for (int ks = 0; ks < 2; ++ks) {
          acc[0][c] = MFMA(a[0][ks], bO[c * 2 + ks], acc[0][c]);
          acc[1][c] = MFMA(a[1][ks], bO[c * 2 + ks], acc[1][c]);
        }
    }
  }

  // epilogue: C frag layout col=lane&15, row=(lane>>4)*4+j
#pragma unroll
  for (int c = 0; c < 3; ++c) {
    int gc = n0 + wid * 48 + c * 16 + lr;
    int mat = gc >> 7, h = gc & 127;
#pragma unroll
    for (int r = 0; r < 2; ++r) {
#pragma unroll
      for (int j = 0; j < 4; ++j) {
        int gr = m0 + r * 16 + lg * 4 + j;
        float val = acc[r][c][j];
        ushort ov = f2bf(mat == 0 ? val * QSCL : val);
        if (mat == 0) {
          qws[(size_t)gr * H_DIM + h] = ov;
        } else if (mat == 1) {
          kws[(size_t)gr * H_DIM + h] = ov;
        } else {
          int b = gr >> 11, t = gr & 2047;
          vtws[((size_t)b * H_DIM + h) * T_LEN + t] = ov;
        }
      }
    }
  }
}

// ---------------------------------------------------------------------------
// Kernel 2a: flash partial pass, block-cooperative LDS-staged K/V
// (unchanged from round 9).
// ---------------------------------------------------------------------------
__global__ __launch_bounds__(256, 3) void attn_part(const ushort* __restrict__ qws,
                                                    const ushort* __restrict__ kws,
                                                    const ushort* __restrict__ vtws,
                                                    float* __restrict__ pml,
                                                    ushort* __restrict__ pacc,
                                                    float* __restrict__ out) {
  __shared__ ushort Klds[64 * KSTR];
  __shared__ ushort Vlds[128 * VSTR];
  __shared__ ushort Pw[4][16 * PSTR];

  const int tid = threadIdx.x;
  const int wid = tid >> 6, lane = tid & 63;
  const int lg = lane >> 4, lr = lane & 15;
  const int bid = blockIdx.x;
  const int b = bid & 7;
  const int item = bid >> 3;

  int qb, ck;
  bool direct;
  if (item < 8) {
    qb = item; ck = 0; direct = true;
  } else {
    const int p = item - 8;
    direct = false;
    if (p < 12)      { int q = p / 3;        qb = 8 + q;  ck = p - q * 3; }
    else if (p < 28) { int q = (p - 12) >> 2; qb = 12 + q; ck = (p - 12) & 3; }
    else if (p < 48) { int q = (p - 28) / 5; qb = 16 + q; ck = (p - 28) - q * 5; }
    else if (p < 72) { int q = (p - 48) / 6; qb = 20 + q; ck = (p - 48) - q * 6; }
    else if (p < 100){ int q = (p - 72) / 7; qb = 24 + q; ck = (p - 72) - q * 7; }
    else             { int q = (p - 100) >> 3; qb = 28 + q; ck = (p - 100) & 7; }
  }
  const int qi = qb * 4 + wid;
  const int q0 = qi * 16;
  const int nt = qb + 1;
  const int kvt_lo = direct ? 0 : ck * 4;
  const int kvt_hi = direct ? nt : min(ck * 4 + 4, nt);
  const size_t tokbase = (size_t)b * T_LEN;
  const ushort* vb = vtws + (size_t)b * H_DIM * T_LEN;

  const int kr = tid >> 2, kseg = tid & 3;
  const int vr = tid >> 1, vseg = tid & 1;
  const ushort* gK = &kws[(tokbase + kr) * H_DIM + kseg * 32];
  const ushort* gV = &vb[(size_t)vr * T_LEN + vseg * 32];

  bf16x8 qf[4];
#pragma unroll
  for (int hk = 0; hk < 4; ++hk)
    qf[hk] = *(const bf16x8*)&qws[(tokbase + q0 + lr) * H_DIM + hk * 32 + lg * 8];

  f32x4 acc[8];
#pragma unroll
  for (int hf = 0; hf < 8; ++hf) acc[hf] = f32x4{0.f, 0.f, 0.f, 0.f};
  float mrun = -INFINITY, lrun = 0.f;

  ushort* Pme = &Pw[wid][0];

  us8 kreg[4], vreg[4];
#pragma unroll
  for (int i = 0; i < 4; ++i) {
    kreg[i] = *(const us8*)(gK + (size_t)kvt_lo * 64 * H_DIM + i * 8);
    vreg[i] = *(const us8*)(gV + kvt_lo * 64 + i * 8);
  }

  for (int kvt = kvt_lo; kvt < kvt_hi; ++kvt) {
    const int kv0 = kvt * 64;

    __syncthreads();
#pragma unroll
    for (int i = 0; i < 4; ++i) {
      *(us8*)&Klds[kr * KSTR + kseg * 32 + i * 8] = kreg[i];
      *(us8*)&Vlds[vr * VSTR + vseg * 32 + i * 8] = vreg[i];
    }
    if (kvt + 1 < kvt_hi) {
#pragma unroll
      for (int i = 0; i < 4; ++i) {
        kreg[i] = *(const us8*)(gK + (size_t)(kv0 + 64) * H_DIM + i * 8);
        vreg[i] = *(const us8*)(gV + kv0 + 64 + i * 8);
      }
    }
    __syncthreads();

    f32x4 s[4];
#pragma unroll
    for (int c = 0; c < 4; ++c) {
      f32x4 sc = f32x4{0.f, 0.f, 0.f, 0.f};
#pragma unroll
      for (int hk = 0; hk < 4; ++hk) {
        bf16x8 kf = *(const bf16x8*)&Klds[(c * 16 + lr) * KSTR + hk * 32 + lg * 8];
        sc = MFMA(kf, qf[hk], sc);
      }
      s[c] = sc;
    }

    if (kvt == nt - 1) {
#pragma unroll
      for (int c = 0; c < 4; ++c)
#pragma unroll
        for (int j = 0; j < 4; ++j) {
          int kv = kv0 + c * 16 + lg * 4 + j;
          if (kv > q0 + lr) s[c][j] = -INFINITY;
        }
    }

    float mx = s[0][0];
#pragma unroll
    for (int c = 0; c < 4; ++c)
#pragma unroll
      for (int j = 0; j < 4; ++j) mx = fmaxf(mx, s[c][j]);
    mx = fmaxf(mx, __shfl_xor(mx, 16));
    mx = fmaxf(mx, __shfl_xor(mx, 32));

    float mnew = fmaxf(mrun, mx);
    float scold = exp2f(mrun - mnew);

    float rsum = 0.f;
#pragma unroll
    for (int c = 0; c < 4; ++c)
#pragma unroll
      for (int j = 0; j < 4; ++j) {
        float p = exp2f(s[c][j] - mnew);
        s[c][j] = p;
        rsum += p;
      }

#pragma unroll
    for (int c = 0; c < 4; ++c) {
      ushort4 u;
      u.x = f2bf(s[c][0]); u.y = f2bf(s[c][1]);
      u.z = f2bf(s[c][2]); u.w = f2bf(s[c][3]);
      *(ushort4*)&Pme[lr * PSTR + c * 16 + lg * 4] = u;
    }

    bf16x8 v0[8];
#pragma unroll
    for (int hf = 0; hf < 8; ++hf)
      v0[hf] = *(const bf16x8*)&Vlds[(hf * 16 + lr) * VSTR + lg * 8];

    rsum += __shfl_xor(rsum, 16);
    rsum += __shfl_xor(rsum, 32);

    lrun = lrun * scold + rsum;
    mrun = mnew;
#pragma unroll
    for (int hf = 0; hf < 8; ++hf)
#pragma unroll
      for (int j = 0; j < 4; ++j) acc[hf][j] *= scold;

    bf16x8 pa0 = *(const bf16x8*)&Pme[lr * PSTR + lg * 8];
    bf16x8 pa1 = *(const bf16x8*)&Pme[lr * PSTR + 32 + lg * 8];

#pragma unroll
    for (int hf = 0; hf < 8; ++hf)
      acc[hf] = MFMA(v0[hf], pa0, acc[hf]);
#pragma unroll
    for (int hf = 0; hf < 8; ++hf) {
      bf16x8 v1 = *(const bf16x8*)&Vlds[(hf * 16 + lr) * VSTR + 32 + lg * 8];
      acc[hf] = MFMA(v1, pa1, acc[hf]);
    }
  }

  if (direct) {
    float inv = 1.0f / lrun;
    float* op = &out[(tokbase + q0 + lr) * H_DIM + lg * 4];
#pragma unroll
    for (int hf = 0; hf < 8; ++hf) {
      float4 r0 = make_float4(acc[hf][0] * inv, acc[hf][1] * inv,
                              acc[hf][2] * inv, acc[hf][3] * inv);
      *(float4*)(op + hf * 16) = r0;
    }
  } else {
    int base;
    if (qi < 48)       base = (qi - 32) * 3;
    else if (qi < 64)  base = 48 + (qi - 48) * 4;
    else if (qi < 80)  base = 112 + (qi - 64) * 5;
    else if (qi < 96)  base = 192 + (qi - 80) * 6;
    else if (qi < 112) base = 288 + (qi - 96) * 7;
    else               base = 400 + (qi - 112) * 8;
    const size_t slot = (size_t)b * SLOTS_PER_B + base + ck;
    if (lg == 0) {
      pml[slot * 32 + lr] = mrun;
      pml[slot * 32 + 16 + lr] = lrun;
    }
    ushort* ap = &pacc[slot * 2048 + (size_t)lr * 128 + lg * 4];
#pragma unroll
    for (int hf = 0; hf < 8; ++hf) {
      ushort4 u;
      u.x = f2bf(acc[hf][0]); u.y = f2bf(acc[hf][1]);
      u.z = f2bf(acc[hf][2]); u.w = f2bf(acc[hf][3]);
      *(ushort4*)(ap + hf * 16) = u;
    }
  }
}

// ---------------------------------------------------------------------------
// Kernel 2b: online merge of 3..8 partials per (b, qi) for qi >= 32.
// (unchanged)
// ---------------------------------------------------------------------------
__global__ __launch_bounds__(256) void attn_merge(const float* __restrict__ pml,
                                                  const ushort* __restrict__ pacc,
                                                  float* __restrict__ out) {
  const int bid = blockIdx.x;
  const int b = bid & 7, qi = (bid >> 3) + 32;
  int base, nch;
  if (qi < 48)       { base = (qi - 32) * 3;        nch = 3; }
  else if (qi < 64)  { base = 48 + (qi - 48) * 4;   nch = 4; }
  else if (qi < 80)  { base = 112 + (qi - 64) * 5;  nch = 5; }
  else if (qi < 96)  { base = 192 + (qi - 80) * 6;  nch = 6; }
  else if (qi < 112) { base = 288 + (qi - 96) * 7;  nch = 7; }
  else               { base = 400 + (qi - 112) * 8; nch = 8; }
  const size_t slot0 = (size_t)b * SLOTS_PER_B + base;
  const int tid = threadIdx.x;
  const int r = tid >> 4, c0 = (tid & 15) * 8;

  float mrun = -INFINITY, L = 0.f;
  float o[8];
#pragma unroll
  for (int i = 0; i < 8; ++i) o[i] = 0.f;

  for (int ck = 0; ck < nch; ++ck) {
    const size_t s = slot0 + ck;
    float m = pml[s * 32 + r];
    float l = pml[s * 32 + 16 + r];
    float mn = fmaxf(mrun, m);
    float sc = exp2f(mrun - mn);
    float w  = exp2f(m - mn);
    L = L * sc + w * l;
    const ushort* ap = &pacc[s * 2048 + (size_t)r * 128 + c0];
    ushort4 u0 = *(const ushort4*)ap;
    ushort4 u1 = *(const ushort4*)(ap + 4);
    o[0] = o[0] * sc + w * bf2f(u0.x); o[1] = o[1] * sc + w * bf2f(u0.y);
    o[2] = o[2] * sc + w * bf2f(u0.z); o[3] = o[3] * sc + w * bf2f(u0.w);
    o[4] = o[4] * sc + w * bf2f(u1.x); o[5] = o[5] * sc + w * bf2f(u1.y);
    o[6] = o[6] * sc + w * bf2f(u1.z); o[7] = o[7] * sc + w * bf2f(u1.w);
    mrun = mn;
  }
  float invL = 1.0f / L;
  float4 r0 = make_float4(o[0] * invL, o[1] * invL, o[2] * invL, o[3] * invL);
  float4 r1 = make_float4(o[4] * invL, o[5] * invL, o[6] * invL, o[7] * invL);
  float* op = &out[((size_t)b * T_LEN + qi * 16 + r) * H_DIM + c0];
  *(float4*)op = r0;
  *(float4*)(op + 4) = r1;
}

// ---------------------------------------------------------------------------
// ws layout identical to rounds 8-10 (total 30,670,848 B, proven fit):
//   [0, 786432) wt (dead after qkv_gemm; pml overlaps, 540,672 B)
//   qws / kws / vtws ; pacc = 8*528 slots * 2048 bf16
// ---------------------------------------------------------------------------
extern "C" void kernel_launch(void* const* d_in, const int* in_sizes, int n_in,
                              void* d_out, int out_size, void* d_ws, size_t ws_size,
                              hipStream_t stream) {
  const float* emb = (const float*)d_in[0];
  const float* Wq  = (const float*)d_in[1];
  const float* Wk  = (const float*)d_in[2];
  const float* Wv  = (const float*)d_in[3];
  float* out = (float*)d_out;

  ushort* wt   = (ushort*)d_ws;
  ushort* qws  = wt  + (size_t)N_COLS * C_DIM;
  ushort* kws  = qws + (size_t)M_ROWS * H_DIM;
  ushort* vtws = kws + (size_t)M_ROWS * H_DIM;
  ushort* pacc = vtws + (size_t)8 * H_DIM * T_LEN;
  float*  pml  = (float*)d_ws;   // overlaps dead wt region

  wt_convert<<<(N_COLS * C_DIM) / 256, 256, 0, stream>>>(Wq, Wk, Wv, wt);
  qkv_gemm<<<(M_ROWS / 32) * 2, 256, 0, stream>>>(emb, wt, qws, kws, vtws);
  attn_part<<<8 * 140, 256, 0, stream>>>(qws, kws, vtws, pml, pacc, out);
  attn_merge<<<8 * 96, 256, 0, stream>>>(pml, pacc, out);
}

// Round 12
// 80.796 us; speedup vs baseline: 1.2475x; 1.2475x over previous
//
#include <hip/hip_runtime.h>
#include <hip/hip_bf16.h>

typedef __bf16 bf16x8 __attribute__((ext_vector_type(8)));
typedef float f32x4 __attribute__((ext_vector_type(4)));
typedef ushort us8 __attribute__((ext_vector_type(8)));

#define MFMA(a, b, c) __builtin_amdgcn_mfma_f32_16x16x32_bf16((a), (b), (c), 0, 0, 0)

static constexpr int T_LEN = 2048;
static constexpr int C_DIM = 1024;
static constexpr int H_DIM = 128;
static constexpr int M_ROWS = 8 * 2048;    // 16384
static constexpr int N_COLS = 384;         // 3 * 128
static constexpr int SLOTS_PER_B = 528;    // partial slots (qi>=32)
static constexpr int PSTR = 72;            // P buffer row stride
static constexpr int KSTR = 136;           // K LDS row stride (272B, 2-way max)
static constexpr int VSTR = 72;            // V LDS row stride (144B, 2-way max)
static constexpr int BSTR = 40;            // qkv LDS row stride (80B, 2-way max)

__device__ __forceinline__ ushort f2bf(float f) {
  union { float f; unsigned u; } v; v.f = f;
  unsigned u = v.u;
  u += 0x7fffu + ((u >> 16) & 1u);
  return (ushort)(u >> 16);
}
__device__ __forceinline__ float bf2f(ushort u) {
  union { unsigned u; float f; } v; v.u = (unsigned)u << 16;
  return v.f;
}

// ---------------------------------------------------------------------------
// Kernel 0: Wq/Wk/Wv fp32 [1024][128] -> bf16 wt_t, K-STEP-TILED layout:
//   wt_t[(kt*384 + gc)*32 + kk] = W(c = kt*32+kk, gc)
// so each K-step's 192-col B-tile is a contiguous 12 KB block.
// ---------------------------------------------------------------------------
__global__ void wt_convert(const float* __restrict__ Wq,
                           const float* __restrict__ Wk,
                           const float* __restrict__ Wv,
                           ushort* __restrict__ wt) {
  int o = blockIdx.x * 256 + threadIdx.x;   // 0..393215
  int kt = o / 12288;                        // 384*32
  int rem = o - kt * 12288;
  int gc = rem >> 5;
  int kk = rem & 31;
  int c  = kt * 32 + kk;
  int mat = gc >> 7;
  int h   = gc & 127;
  const float* W = (mat == 0) ? Wq : ((mat == 1) ? Wk : Wv);
  wt[o] = f2bf(W[c * H_DIM + h]);
}

// ---------------------------------------------------------------------------
// Kernel 1: fused QKV projection v3 — BOTH operands LDS-staged with fully
// COALESCED global reads (wt_t tiled layout kills the 16-way row scatter
// that pinned every previous variant at ~64 us). BM=32, BN=192, BK=32,
// 256 thr (4 waves), 1024 blocks, 4 blocks/CU (LDS 35 KB).
// Round-9-proven staging pattern: barrier / write regs->LDS / prefetch
// next-tile regs / barrier / compute.
// ---------------------------------------------------------------------------
__global__ __launch_bounds__(256, 4) void qkv_gemm(const float* __restrict__ X,
                                                   const ushort* __restrict__ wt,
                                                   ushort* __restrict__ qws,
                                                   ushort* __restrict__ kws,
                                                   ushort* __restrict__ vtws) {
  __shared__ ushort As[2][32 * BSTR];    //  5120 B
  __shared__ ushort Bs[2][192 * BSTR];   // 30720 B
  const int tid = threadIdx.x;
  const int wid = tid >> 6, lane = tid & 63;
  const int lg = lane >> 4, lr = lane & 15;
  const int m0 = (blockIdx.x >> 1) * 32;
  const int n0 = (blockIdx.x & 1) * 192;
  const float QSCL = 0.03125f * 1.44269504f;

  // A staging: thread -> (row ar, 4 floats at ac*4); coalesced per row
  const int ar = tid >> 3, ac = tid & 7;
  const float* gA = &X[(size_t)(m0 + ar) * C_DIM + ac * 4];

  // B staging: 48B/thread from the contiguous 12KB K-step block
  // u_i = tid*24 + i*8 (ushort idx) -> row u>>5, col u&31
  const int u0 = tid * 24;
  const int br0 = u0 >> 5,        bk0 = u0 & 31;
  const int br1 = (u0 + 8) >> 5,  bk1 = (u0 + 8) & 31;
  const int br2 = (u0 + 16) >> 5, bk2 = (u0 + 16) & 31;

  f32x4 acc[2][3];
#pragma unroll
  for (int r = 0; r < 2; ++r)
#pragma unroll
    for (int c = 0; c < 3; ++c)
      acc[r][c] = f32x4{0.f, 0.f, 0.f, 0.f};

  // prologue: load tile 0 into regs
  float4 areg = *(const float4*)gA;
  const ushort* gB0 = &wt[(size_t)(0 * 384 + n0) * 32 + u0];
  us8 breg0 = *(const us8*)(gB0);
  us8 breg1 = *(const us8*)(gB0 + 8);
  us8 breg2 = *(const us8*)(gB0 + 16);

  for (int kt = 0; kt < 32; ++kt) {
    const int cur = kt & 1;
    __syncthreads();   // everyone done reading buf[cur] from 2 iters ago
    {
      ushort4 av;
      av.x = f2bf(areg.x); av.y = f2bf(areg.y);
      av.z = f2bf(areg.z); av.w = f2bf(areg.w);
      *(ushort4*)&As[cur][ar * BSTR + ac * 4] = av;
      *(us8*)&Bs[cur][br0 * BSTR + bk0] = breg0;
      *(us8*)&Bs[cur][br1 * BSTR + bk1] = breg1;
      *(us8*)&Bs[cur][br2 * BSTR + bk2] = breg2;
    }
    if (kt + 1 < 32) {
      areg = *(const float4*)(gA + (kt + 1) * 32);
      const ushort* gB = &wt[(size_t)((kt + 1) * 384 + n0) * 32 + u0];
      breg0 = *(const us8*)(gB);
      breg1 = *(const us8*)(gB + 8);
      breg2 = *(const us8*)(gB + 16);
    }
    __syncthreads();   // staged tile visible

    bf16x8 a0 = *(const bf16x8*)&As[cur][(lr) * BSTR + lg * 8];
    bf16x8 a1 = *(const bf16x8*)&As[cur][(16 + lr) * BSTR + lg * 8];
#pragma unroll
    for (int c = 0; c < 3; ++c) {
      bf16x8 bf = *(const bf16x8*)&Bs[cur][(wid * 48 + c * 16 + lr) * BSTR + lg * 8];
      acc[0][c] = MFMA(a0, bf, acc[0][c]);
      acc[1][c] = MFMA(a1, bf, acc[1][c]);
    }
  }

  // epilogue: C frag layout col=lane&15, row=(lane>>4)*4+j
#pragma unroll
  for (int c = 0; c < 3; ++c) {
    int gc = n0 + wid * 48 + c * 16 + lr;
    int mat = gc >> 7, h = gc & 127;
#pragma unroll
    for (int r = 0; r < 2; ++r) {
#pragma unroll
      for (int j = 0; j < 4; ++j) {
        int gr = m0 + r * 16 + lg * 4 + j;
        float val = acc[r][c][j];
        ushort ov = f2bf(mat == 0 ? val * QSCL : val);
        if (mat == 0) {
          qws[(size_t)gr * H_DIM + h] = ov;
        } else if (mat == 1) {
          kws[(size_t)gr * H_DIM + h] = ov;
        } else {
          int b = gr >> 11, t = gr & 2047;
          vtws[((size_t)b * H_DIM + h) * T_LEN + t] = ov;
        }
      }
    }
  }
}

// ---------------------------------------------------------------------------
// Kernel 2a: flash partial pass, block-cooperative LDS-staged K/V
// (unchanged from round 9).
// ---------------------------------------------------------------------------
__global__ __launch_bounds__(256, 3) void attn_part(const ushort* __restrict__ qws,
                                                    const ushort* __restrict__ kws,
                                                    const ushort* __restrict__ vtws,
                                                    float* __restrict__ pml,
                                                    ushort* __restrict__ pacc,
                                                    float* __restrict__ out) {
  __shared__ ushort Klds[64 * KSTR];
  __shared__ ushort Vlds[128 * VSTR];
  __shared__ ushort Pw[4][16 * PSTR];

  const int tid = threadIdx.x;
  const int wid = tid >> 6, lane = tid & 63;
  const int lg = lane >> 4, lr = lane & 15;
  const int bid = blockIdx.x;
  const int b = bid & 7;
  const int item = bid >> 3;

  int qb, ck;
  bool direct;
  if (item < 8) {
    qb = item; ck = 0; direct = true;
  } else {
    const int p = item - 8;
    direct = false;
    if (p < 12)      { int q = p / 3;        qb = 8 + q;  ck = p - q * 3; }
    else if (p < 28) { int q = (p - 12) >> 2; qb = 12 + q; ck = (p - 12) & 3; }
    else if (p < 48) { int q = (p - 28) / 5; qb = 16 + q; ck = (p - 28) - q * 5; }
    else if (p < 72) { int q = (p - 48) / 6; qb = 20 + q; ck = (p - 48) - q * 6; }
    else if (p < 100){ int q = (p - 72) / 7; qb = 24 + q; ck = (p - 72) - q * 7; }
    else             { int q = (p - 100) >> 3; qb = 28 + q; ck = (p - 100) & 7; }
  }
  const int qi = qb * 4 + wid;
  const int q0 = qi * 16;
  const int nt = qb + 1;
  const int kvt_lo = direct ? 0 : ck * 4;
  const int kvt_hi = direct ? nt : min(ck * 4 + 4, nt);
  const size_t tokbase = (size_t)b * T_LEN;
  const ushort* vb = vtws + (size_t)b * H_DIM * T_LEN;

  const int kr = tid >> 2, kseg = tid & 3;
  const int vr = tid >> 1, vseg = tid & 1;
  const ushort* gK = &kws[(tokbase + kr) * H_DIM + kseg * 32];
  const ushort* gV = &vb[(size_t)vr * T_LEN + vseg * 32];

  bf16x8 qf[4];
#pragma unroll
  for (int hk = 0; hk < 4; ++hk)
    qf[hk] = *(const bf16x8*)&qws[(tokbase + q0 + lr) * H_DIM + hk * 32 + lg * 8];

  f32x4 acc[8];
#pragma unroll
  for (int hf = 0; hf < 8; ++hf) acc[hf] = f32x4{0.f, 0.f, 0.f, 0.f};
  float mrun = -INFINITY, lrun = 0.f;

  ushort* Pme = &Pw[wid][0];

  us8 kreg[4], vreg[4];
#pragma unroll
  for (int i = 0; i < 4; ++i) {
    kreg[i] = *(const us8*)(gK + (size_t)kvt_lo * 64 * H_DIM + i * 8);
    vreg[i] = *(const us8*)(gV + kvt_lo * 64 + i * 8);
  }

  for (int kvt = kvt_lo; kvt < kvt_hi; ++kvt) {
    const int kv0 = kvt * 64;

    __syncthreads();
#pragma unroll
    for (int i = 0; i < 4; ++i) {
      *(us8*)&Klds[kr * KSTR + kseg * 32 + i * 8] = kreg[i];
      *(us8*)&Vlds[vr * VSTR + vseg * 32 + i * 8] = vreg[i];
    }
    if (kvt + 1 < kvt_hi) {
#pragma unroll
      for (int i = 0; i < 4; ++i) {
        kreg[i] = *(const us8*)(gK + (size_t)(kv0 + 64) * H_DIM + i * 8);
        vreg[i] = *(const us8*)(gV + kv0 + 64 + i * 8);
      }
    }
    __syncthreads();

    f32x4 s[4];
#pragma unroll
    for (int c = 0; c < 4; ++c) {
      f32x4 sc = f32x4{0.f, 0.f, 0.f, 0.f};
#pragma unroll
      for (int hk = 0; hk < 4; ++hk) {
        bf16x8 kf = *(const bf16x8*)&Klds[(c * 16 + lr) * KSTR + hk * 32 + lg * 8];
        sc = MFMA(kf, qf[hk], sc);
      }
      s[c] = sc;
    }

    if (kvt == nt - 1) {
#pragma unroll
      for (int c = 0; c < 4; ++c)
#pragma unroll
        for (int j = 0; j < 4; ++j) {
          int kv = kv0 + c * 16 + lg * 4 + j;
          if (kv > q0 + lr) s[c][j] = -INFINITY;
        }
    }

    float mx = s[0][0];
#pragma unroll
    for (int c = 0; c < 4; ++c)
#pragma unroll
      for (int j = 0; j < 4; ++j) mx = fmaxf(mx, s[c][j]);
    mx = fmaxf(mx, __shfl_xor(mx, 16));
    mx = fmaxf(mx, __shfl_xor(mx, 32));

    float mnew = fmaxf(mrun, mx);
    float scold = exp2f(mrun - mnew);

    float rsum = 0.f;
#pragma unroll
    for (int c = 0; c < 4; ++c)
#pragma unroll
      for (int j = 0; j < 4; ++j) {
        float p = exp2f(s[c][j] - mnew);
        s[c][j] = p;
        rsum += p;
      }

#pragma unroll
    for (int c = 0; c < 4; ++c) {
      ushort4 u;
      u.x = f2bf(s[c][0]); u.y = f2bf(s[c][1]);
      u.z = f2bf(s[c][2]); u.w = f2bf(s[c][3]);
      *(ushort4*)&Pme[lr * PSTR + c * 16 + lg * 4] = u;
    }

    bf16x8 v0[8];
#pragma unroll
    for (int hf = 0; hf < 8; ++hf)
      v0[hf] = *(const bf16x8*)&Vlds[(hf * 16 + lr) * VSTR + lg * 8];

    rsum += __shfl_xor(rsum, 16);
    rsum += __shfl_xor(rsum, 32);

    lrun = lrun * scold + rsum;
    mrun = mnew;
#pragma unroll
    for (int hf = 0; hf < 8; ++hf)
#pragma unroll
      for (int j = 0; j < 4; ++j) acc[hf][j] *= scold;

    bf16x8 pa0 = *(const bf16x8*)&Pme[lr * PSTR + lg * 8];
    bf16x8 pa1 = *(const bf16x8*)&Pme[lr * PSTR + 32 + lg * 8];

#pragma unroll
    for (int hf = 0; hf < 8; ++hf)
      acc[hf] = MFMA(v0[hf], pa0, acc[hf]);
#pragma unroll
    for (int hf = 0; hf < 8; ++hf) {
      bf16x8 v1 = *(const bf16x8*)&Vlds[(hf * 16 + lr) * VSTR + 32 + lg * 8];
      acc[hf] = MFMA(v1, pa1, acc[hf]);
    }
  }

  if (direct) {
    float inv = 1.0f / lrun;
    float* op = &out[(tokbase + q0 + lr) * H_DIM + lg * 4];
#pragma unroll
    for (int hf = 0; hf < 8; ++hf) {
      float4 r0 = make_float4(acc[hf][0] * inv, acc[hf][1] * inv,
                              acc[hf][2] * inv, acc[hf][3] * inv);
      *(float4*)(op + hf * 16) = r0;
    }
  } else {
    int base;
    if (qi < 48)       base = (qi - 32) * 3;
    else if (qi < 64)  base = 48 + (qi - 48) * 4;
    else if (qi < 80)  base = 112 + (qi - 64) * 5;
    else if (qi < 96)  base = 192 + (qi - 80) * 6;
    else if (qi < 112) base = 288 + (qi - 96) * 7;
    else               base = 400 + (qi - 112) * 8;
    const size_t slot = (size_t)b * SLOTS_PER_B + base + ck;
    if (lg == 0) {
      pml[slot * 32 + lr] = mrun;
      pml[slot * 32 + 16 + lr] = lrun;
    }
    ushort* ap = &pacc[slot * 2048 + (size_t)lr * 128 + lg * 4];
#pragma unroll
    for (int hf = 0; hf < 8; ++hf) {
      ushort4 u;
      u.x = f2bf(acc[hf][0]); u.y = f2bf(acc[hf][1]);
      u.z = f2bf(acc[hf][2]); u.w = f2bf(acc[hf][3]);
      *(ushort4*)(ap + hf * 16) = u;
    }
  }
}

// ---------------------------------------------------------------------------
// Kernel 2b: online merge of 3..8 partials per (b, qi) for qi >= 32.
// (unchanged)
// ---------------------------------------------------------------------------
__global__ __launch_bounds__(256) void attn_merge(const float* __restrict__ pml,
                                                  const ushort* __restrict__ pacc,
                                                  float* __restrict__ out) {
  const int bid = blockIdx.x;
  const int b = bid & 7, qi = (bid >> 3) + 32;
  int base, nch;
  if (qi < 48)       { base = (qi - 32) * 3;        nch = 3; }
  else if (qi < 64)  { base = 48 + (qi - 48) * 4;   nch = 4; }
  else if (qi < 80)  { base = 112 + (qi - 64) * 5;  nch = 5; }
  else if (qi < 96)  { base = 192 + (qi - 80) * 6;  nch = 6; }
  else if (qi < 112) { base = 288 + (qi - 96) * 7;  nch = 7; }
  else               { base = 400 + (qi - 112) * 8; nch = 8; }
  const size_t slot0 = (size_t)b * SLOTS_PER_B + base;
  const int tid = threadIdx.x;
  const int r = tid >> 4, c0 = (tid & 15) * 8;

  float mrun = -INFINITY, L = 0.f;
  float o[8];
#pragma unroll
  for (int i = 0; i < 8; ++i) o[i] = 0.f;

  for (int ck = 0; ck < nch; ++ck) {
    const size_t s = slot0 + ck;
    float m = pml[s * 32 + r];
    float l = pml[s * 32 + 16 + r];
    float mn = fmaxf(mrun, m);
    float sc = exp2f(mrun - mn);
    float w  = exp2f(m - mn);
    L = L * sc + w * l;
    const ushort* ap = &pacc[s * 2048 + (size_t)r * 128 + c0];
    ushort4 u0 = *(const ushort4*)ap;
    ushort4 u1 = *(const ushort4*)(ap + 4);
    o[0] = o[0] * sc + w * bf2f(u0.x); o[1] = o[1] * sc + w * bf2f(u0.y);
    o[2] = o[2] * sc + w * bf2f(u0.z); o[3] = o[3] * sc + w * bf2f(u0.w);
    o[4] = o[4] * sc + w * bf2f(u1.x); o[5] = o[5] * sc + w * bf2f(u1.y);
    o[6] = o[6] * sc + w * bf2f(u1.z); o[7] = o[7] * sc + w * bf2f(u1.w);
    mrun = mn;
  }
  float invL = 1.0f / L;
  float4 r0 = make_float4(o[0] * invL, o[1] * invL, o[2] * invL, o[3] * invL);
  float4 r1 = make_float4(o[4] * invL, o[5] * invL, o[6] * invL, o[7] * invL);
  float* op = &out[((size_t)b * T_LEN + qi * 16 + r) * H_DIM + c0];
  *(float4*)op = r0;
  *(float4*)(op + 4) = r1;
}

// ---------------------------------------------------------------------------
// ws layout identical to rounds 8-11 (total 30,670,848 B, proven fit):
//   [0, 786432) wt_t (dead after qkv_gemm; pml overlaps, 540,672 B)
//   qws / kws / vtws ; pacc = 8*528 slots * 2048 bf16
// ---------------------------------------------------------------------------
extern "C" void kernel_launch(void* const* d_in, const int* in_sizes, int n_in,
                              void* d_out, int out_size, void* d_ws, size_t ws_size,
                              hipStream_t stream) {
  const float* emb = (const float*)d_in[0];
  const float* Wq  = (const float*)d_in[1];
  const float* Wk  = (const float*)d_in[2];
  const float* Wv  = (const float*)d_in[3];
  float* out = (float*)d_out;

  ushort* wt   = (ushort*)d_ws;
  ushort* qws  = wt  + (size_t)N_COLS * C_DIM;
  ushort* kws  = qws + (size_t)M_ROWS * H_DIM;
  ushort* vtws = kws + (size_t)M_ROWS * H_DIM;
  ushort* pacc = vtws + (size_t)8 * H_DIM * T_LEN;
  float*  pml  = (float*)d_ws;   // overlaps dead wt region

  wt_convert<<<(N_COLS * C_DIM) / 256, 256, 0, stream>>>(Wq, Wk, Wv, wt);
  qkv_gemm<<<(M_ROWS / 32) * 2, 256, 0, stream>>>(emb, wt, qws, kws, vtws);
  attn_part<<<8 * 140, 256, 0, stream>>>(qws, kws, vtws, pml, pacc, out);
  attn_merge<<<8 * 96, 256, 0, stream>>>(pml, pacc, out);
}

// Round 14
// 72.752 us; speedup vs baseline: 1.3855x; 1.1106x over previous
//
#include <hip/hip_runtime.h>
#include <hip/hip_bf16.h>

typedef __bf16 bf16x8 __attribute__((ext_vector_type(8)));
typedef float f32x4 __attribute__((ext_vector_type(4)));
typedef ushort us8 __attribute__((ext_vector_type(8)));

#define MFMA(a, b, c) __builtin_amdgcn_mfma_f32_16x16x32_bf16((a), (b), (c), 0, 0, 0)

static constexpr int T_LEN = 2048;
static constexpr int C_DIM = 1024;
static constexpr int H_DIM = 128;
static constexpr int M_ROWS = 8 * 2048;    // 16384
static constexpr int N_COLS = 384;         // 3 * 128
static constexpr int SLOTS_PER_B = 528;    // partial slots (qi>=32)
static constexpr int PSTR = 72;            // P buffer row stride
static constexpr int KSTR = 136;           // K LDS row stride (272B, 2-way max)
static constexpr int VSTR = 72;            // V LDS row stride (144B, 2-way max)

__device__ __forceinline__ ushort f2bf(float f) {
  union { float f; unsigned u; } v; v.f = f;
  unsigned u = v.u;
  u += 0x7fffu + ((u >> 16) & 1u);
  return (ushort)(u >> 16);
}
__device__ __forceinline__ float bf2f(ushort u) {
  union { unsigned u; float f; } v; v.u = (unsigned)u << 16;
  return v.f;
}

// raw barrier: lgkmcnt(0) for LDS visibility, NO vmcnt drain.
__device__ __forceinline__ void waitbar() {
  asm volatile("s_waitcnt lgkmcnt(0)" ::: "memory");
  __builtin_amdgcn_s_barrier();
  __builtin_amdgcn_sched_barrier(0);
}

// paired-row swizzled LDS byte address for logical (row, 16B-slot):
//   [R][32 ushorts] stored as [R/2][64 ushorts];
//   byte = (row>>1)*128 + (row&1)*64 + ((slot*16) ^ (((row>>1)&3)<<4))
// XOR field is 2 bits — exactly the slot field width (bijective within the
// 64B half-row; round-13's &7 overflowed into neighboring rows).
__device__ __forceinline__ int swz_byte(int row, int slot) {
  return (row >> 1) * 128 + (row & 1) * 64 + ((slot * 16) ^ (((row >> 1) & 3) << 4));
}

// ---------------------------------------------------------------------------
// Kernel 0: Wq/Wk/Wv fp32 [1024][128] -> bf16 wt_t, K-STEP-TILED layout:
//   wt_t[(kt*384 + gc)*32 + kk] = W(c = kt*32+kk, gc)
// ---------------------------------------------------------------------------
__global__ void wt_convert(const float* __restrict__ Wq,
                           const float* __restrict__ Wk,
                           const float* __restrict__ Wv,
                           ushort* __restrict__ wt) {
  int o = blockIdx.x * 256 + threadIdx.x;   // 0..393215
  int kt = o / 12288;                        // 384*32
  int rem = o - kt * 12288;
  int gc = rem >> 5;
  int kk = rem & 31;
  int c  = kt * 32 + kk;
  int mat = gc >> 7;
  int h   = gc & 127;
  const float* W = (mat == 0) ? Wq : ((mat == 1) ? Wk : Wv);
  wt[o] = f2bf(W[c * H_DIM + h]);
}

// ---------------------------------------------------------------------------
// Kernel 1: fused QKV projection v4 (swizzle-fixed).
//  - BM=64, BN=192, BK=32 -> 512 blocks (2/CU), 12 MFMA/wave/iter
//  - paired-row XOR-swizzled LDS (2-way max, re-verified with &3 mask)
//  - prefetch distance 2 (E/O named reg sets), ONE raw barrier per iter
// ---------------------------------------------------------------------------
__global__ __launch_bounds__(256, 2) void qkv_gemm(const float* __restrict__ X,
                                                   const ushort* __restrict__ wt,
                                                   ushort* __restrict__ qws,
                                                   ushort* __restrict__ kws,
                                                   ushort* __restrict__ vtws) {
  __shared__ ushort As[2][32 * 64];   // logical [64][32] paired -> 4 KB each
  __shared__ ushort Bs[2][96 * 64];   // logical [192][32] paired -> 12 KB each
  const int tid = threadIdx.x;
  const int wid = tid >> 6, lane = tid & 63;
  const int lg = lane >> 4, lr = lane & 15;
  const int m0 = (blockIdx.x >> 1) * 64;
  const int n0 = (blockIdx.x & 1) * 192;
  const float QSCL = 0.03125f * 1.44269504f;

  // A staging: ar = tid>>2 (0..63), ac = tid&3 -> 8 floats at col ac*8
  const int ar = tid >> 2, ac = tid & 3;
  const float* gA = &X[(size_t)(m0 + ar) * C_DIM + ac * 8];
  const int awb = swz_byte(ar, ac);

  // B staging: slot-strided, s = tid + 256k (k=0..2) -> lane-contiguous 1KB/instr
  const int bwb0 = swz_byte((tid) >> 2, (tid) & 3);
  const int bwb1 = swz_byte((tid + 256) >> 2, (tid + 256) & 3);
  const int bwb2 = swz_byte((tid + 512) >> 2, (tid + 512) & 3);

  // fragment read bases (row-step of 16 -> +1024 B exactly, since 8 mod 4 == 0)
  const int afb = swz_byte(lr, lg);             // + r*1024 for r=0..3
  const int bfb = swz_byte(wid * 48 + lr, lg);  // + c*1024 for c=0..2

  f32x4 acc[4][3];
#pragma unroll
  for (int r = 0; r < 4; ++r)
#pragma unroll
    for (int c = 0; c < 3; ++c)
      acc[r][c] = f32x4{0.f, 0.f, 0.f, 0.f};

  float4 aE0, aE1, aO0, aO1;
  us8 bE0, bE1, bE2, bO0, bO1, bO2;

  // ---- prologue: tile0 -> LDS buf0 directly; tile1 -> E; tile2 -> O ----
  {
    float4 x0 = *(const float4*)gA;
    float4 x1 = *(const float4*)(gA + 4);
    const ushort* gB = &wt[(size_t)n0 * 32];
    us8 b0 = *(const us8*)(gB + (size_t)tid * 8);
    us8 b1 = *(const us8*)(gB + (size_t)(tid + 256) * 8);
    us8 b2 = *(const us8*)(gB + (size_t)(tid + 512) * 8);
    us8 av;
    av[0] = f2bf(x0.x); av[1] = f2bf(x0.y); av[2] = f2bf(x0.z); av[3] = f2bf(x0.w);
    av[4] = f2bf(x1.x); av[5] = f2bf(x1.y); av[6] = f2bf(x1.z); av[7] = f2bf(x1.w);
    *(us8*)((char*)&As[0][0] + awb) = av;
    *(us8*)((char*)&Bs[0][0] + bwb0) = b0;
    *(us8*)((char*)&Bs[0][0] + bwb1) = b1;
    *(us8*)((char*)&Bs[0][0] + bwb2) = b2;
  }
  {
    aE0 = *(const float4*)(gA + 32);
    aE1 = *(const float4*)(gA + 36);
    const ushort* gB = &wt[(size_t)(384 + n0) * 32];
    bE0 = *(const us8*)(gB + (size_t)tid * 8);
    bE1 = *(const us8*)(gB + (size_t)(tid + 256) * 8);
    bE2 = *(const us8*)(gB + (size_t)(tid + 512) * 8);
    aO0 = *(const float4*)(gA + 64);
    aO1 = *(const float4*)(gA + 68);
    const ushort* gB2 = &wt[(size_t)(2 * 384 + n0) * 32];
    bO0 = *(const us8*)(gB2 + (size_t)tid * 8);
    bO1 = *(const us8*)(gB2 + (size_t)(tid + 256) * 8);
    bO2 = *(const us8*)(gB2 + (size_t)(tid + 512) * 8);
  }
  waitbar();   // tile0 staged & visible

  for (int k2 = 0; k2 < 32; k2 += 2) {
    // ======== even iter kt=k2: compute buf0; write tile k2+1 (E) -> buf1;
    //          issue tile k2+3 -> E ========
    {
      us8 av;
      av[0] = f2bf(aE0.x); av[1] = f2bf(aE0.y); av[2] = f2bf(aE0.z); av[3] = f2bf(aE0.w);
      av[4] = f2bf(aE1.x); av[5] = f2bf(aE1.y); av[6] = f2bf(aE1.z); av[7] = f2bf(aE1.w);
      *(us8*)((char*)&As[1][0] + awb) = av;
      *(us8*)((char*)&Bs[1][0] + bwb0) = bE0;
      *(us8*)((char*)&Bs[1][0] + bwb1) = bE1;
      *(us8*)((char*)&Bs[1][0] + bwb2) = bE2;
    }
    if (k2 + 3 < 32) {
      aE0 = *(const float4*)(gA + (k2 + 3) * 32);
      aE1 = *(const float4*)(gA + (k2 + 3) * 32 + 4);
      const ushort* gB = &wt[(size_t)((k2 + 3) * 384 + n0) * 32];
      bE0 = *(const us8*)(gB + (size_t)tid * 8);
      bE1 = *(const us8*)(gB + (size_t)(tid + 256) * 8);
      bE2 = *(const us8*)(gB + (size_t)(tid + 512) * 8);
    }
    {
      bf16x8 a0 = *(const bf16x8*)((const char*)&As[0][0] + afb);
      bf16x8 a1 = *(const bf16x8*)((const char*)&As[0][0] + afb + 1024);
      bf16x8 a2 = *(const bf16x8*)((const char*)&As[0][0] + afb + 2048);
      bf16x8 a3 = *(const bf16x8*)((const char*)&As[0][0] + afb + 3072);
#pragma unroll
      for (int c = 0; c < 3; ++c) {
        bf16x8 bf = *(const bf16x8*)((const char*)&Bs[0][0] + bfb + c * 1024);
        acc[0][c] = MFMA(a0, bf, acc[0][c]);
        acc[1][c] = MFMA(a1, bf, acc[1][c]);
        acc[2][c] = MFMA(a2, bf, acc[2][c]);
        acc[3][c] = MFMA(a3, bf, acc[3][c]);
      }
    }
    waitbar();

    // ======== odd iter kt=k2+1: compute buf1; write tile k2+2 (O) -> buf0;
    //          issue tile k2+4 -> O ========
    if (k2 + 2 < 32) {
      us8 av;
      av[0] = f2bf(aO0.x); av[1] = f2bf(aO0.y); av[2] = f2bf(aO0.z); av[3] = f2bf(aO0.w);
      av[4] = f2bf(aO1.x); av[5] = f2bf(aO1.y); av[6] = f2bf(aO1.z); av[7] = f2bf(aO1.w);
      *(us8*)((char*)&As[0][0] + awb) = av;
      *(us8*)((char*)&Bs[0][0] + bwb0) = bO0;
      *(us8*)((char*)&Bs[0][0] + bwb1) = bO1;
      *(us8*)((char*)&Bs[0][0] + bwb2) = bO2;
    }
    if (k2 + 4 < 32) {
      aO0 = *(const float4*)(gA + (k2 + 4) * 32);
      aO1 = *(const float4*)(gA + (k2 + 4) * 32 + 4);
      const ushort* gB = &wt[(size_t)((k2 + 4) * 384 + n0) * 32];
      bO0 = *(const us8*)(gB + (size_t)tid * 8);
      bO1 = *(const us8*)(gB + (size_t)(tid + 256) * 8);
      bO2 = *(const us8*)(gB + (size_t)(tid + 512) * 8);
    }
    {
      bf16x8 a0 = *(const bf16x8*)((const char*)&As[1][0] + afb);
      bf16x8 a1 = *(const bf16x8*)((const char*)&As[1][0] + afb + 1024);
      bf16x8 a2 = *(const bf16x8*)((const char*)&As[1][0] + afb + 2048);
      bf16x8 a3 = *(const bf16x8*)((const char*)&As[1][0] + afb + 3072);
#pragma unroll
      for (int c = 0; c < 3; ++c) {
        bf16x8 bf = *(const bf16x8*)((const char*)&Bs[1][0] + bfb + c * 1024);
        acc[0][c] = MFMA(a0, bf, acc[0][c]);
        acc[1][c] = MFMA(a1, bf, acc[1][c]);
        acc[2][c] = MFMA(a2, bf, acc[2][c]);
        acc[3][c] = MFMA(a3, bf, acc[3][c]);
      }
    }
    waitbar();
  }

  // epilogue: C frag layout col=lane&15, row=(lane>>4)*4+j
#pragma unroll
  for (int c = 0; c < 3; ++c) {
    int gc = n0 + wid * 48 + c * 16 + lr;
    int mat = gc >> 7, h = gc & 127;
#pragma unroll
    for (int r = 0; r < 4; ++r) {
#pragma unroll
      for (int j = 0; j < 4; ++j) {
        int gr = m0 + r * 16 + lg * 4 + j;
        float val = acc[r][c][j];
        ushort ov = f2bf(mat == 0 ? val * QSCL : val);
        if (mat == 0) {
          qws[(size_t)gr * H_DIM + h] = ov;
        } else if (mat == 1) {
          kws[(size_t)gr * H_DIM + h] = ov;
        } else {
          int b = gr >> 11, t = gr & 2047;
          vtws[((size_t)b * H_DIM + h) * T_LEN + t] = ov;
        }
      }
    }
  }
}

// ---------------------------------------------------------------------------
// Kernel 2a: flash partial pass, block-cooperative LDS-staged K/V
// (unchanged from round 9/12).
// ---------------------------------------------------------------------------
__global__ __launch_bounds__(256, 3) void attn_part(const ushort* __restrict__ qws,
                                                    const ushort* __restrict__ kws,
                                                    const ushort* __restrict__ vtws,
                                                    float* __restrict__ pml,
                                                    ushort* __restrict__ pacc,
                                                    float* __restrict__ out) {
  __shared__ ushort Klds[64 * KSTR];
  __shared__ ushort Vlds[128 * VSTR];
  __shared__ ushort Pw[4][16 * PSTR];

  const int tid = threadIdx.x;
  const int wid = tid >> 6, lane = tid & 63;
  const int lg = lane >> 4, lr = lane & 15;
  const int bid = blockIdx.x;
  const int b = bid & 7;
  const int item = bid >> 3;

  int qb, ck;
  bool direct;
  if (item < 8) {
    qb = item; ck = 0; direct = true;
  } else {
    const int p = item - 8;
    direct = false;
    if (p < 12)      { int q = p / 3;        qb = 8 + q;  ck = p - q * 3; }
    else if (p < 28) { int q = (p - 12) >> 2; qb = 12 + q; ck = (p - 12) & 3; }
    else if (p < 48) { int q = (p - 28) / 5; qb = 16 + q; ck = (p - 28) - q * 5; }
    else if (p < 72) { int q = (p - 48) / 6; qb = 20 + q; ck = (p - 48) - q * 6; }
    else if (p < 100){ int q = (p - 72) / 7; qb = 24 + q; ck = (p - 72) - q * 7; }
    else             { int q = (p - 100) >> 3; qb = 28 + q; ck = (p - 100) & 7; }
  }
  const int qi = qb * 4 + wid;
  const int q0 = qi * 16;
  const int nt = qb + 1;
  const int kvt_lo = direct ? 0 : ck * 4;
  const int kvt_hi = direct ? nt : min(ck * 4 + 4, nt);
  const size_t tokbase = (size_t)b * T_LEN;
  const ushort* vb = vtws + (size_t)b * H_DIM * T_LEN;

  const int kr = tid >> 2, kseg = tid & 3;
  const int vr = tid >> 1, vseg = tid & 1;
  const ushort* gK = &kws[(tokbase + kr) * H_DIM + kseg * 32];
  const ushort* gV = &vb[(size_t)vr * T_LEN + vseg * 32];

  bf16x8 qf[4];
#pragma unroll
  for (int hk = 0; hk < 4; ++hk)
    qf[hk] = *(const bf16x8*)&qws[(tokbase + q0 + lr) * H_DIM + hk * 32 + lg * 8];

  f32x4 acc[8];
#pragma unroll
  for (int hf = 0; hf < 8; ++hf) acc[hf] = f32x4{0.f, 0.f, 0.f, 0.f};
  float mrun = -INFINITY, lrun = 0.f;

  ushort* Pme = &Pw[wid][0];

  us8 kreg[4], vreg[4];
#pragma unroll
  for (int i = 0; i < 4; ++i) {
    kreg[i] = *(const us8*)(gK + (size_t)kvt_lo * 64 * H_DIM + i * 8);
    vreg[i] = *(const us8*)(gV + kvt_lo * 64 + i * 8);
  }

  for (int kvt = kvt_lo; kvt < kvt_hi; ++kvt) {
    const int kv0 = kvt * 64;

    __syncthreads();
#pragma unroll
    for (int i = 0; i < 4; ++i) {
      *(us8*)&Klds[kr * KSTR + kseg * 32 + i * 8] = kreg[i];
      *(us8*)&Vlds[vr * VSTR + vseg * 32 + i * 8] = vreg[i];
    }
    if (kvt + 1 < kvt_hi) {
#pragma unroll
      for (int i = 0; i < 4; ++i) {
        kreg[i] = *(const us8*)(gK + (size_t)(kv0 + 64) * H_DIM + i * 8);
        vreg[i] = *(const us8*)(gV + kv0 + 64 + i * 8);
      }
    }
    __syncthreads();

    f32x4 s[4];
#pragma unroll
    for (int c = 0; c < 4; ++c) {
      f32x4 sc = f32x4{0.f, 0.f, 0.f, 0.f};
#pragma unroll
      for (int hk = 0; hk < 4; ++hk) {
        bf16x8 kf = *(const bf16x8*)&Klds[(c * 16 + lr) * KSTR + hk * 32 + lg * 8];
        sc = MFMA(kf, qf[hk], sc);
      }
      s[c] = sc;
    }

    if (kvt == nt - 1) {
#pragma unroll
      for (int c = 0; c < 4; ++c)
#pragma unroll
        for (int j = 0; j < 4; ++j) {
          int kv = kv0 + c * 16 + lg * 4 + j;
          if (kv > q0 + lr) s[c][j] = -INFINITY;
        }
    }

    float mx = s[0][0];
#pragma unroll
    for (int c = 0; c < 4; ++c)
#pragma unroll
      for (int j = 0; j < 4; ++j) mx = fmaxf(mx, s[c][j]);
    mx = fmaxf(mx, __shfl_xor(mx, 16));
    mx = fmaxf(mx, __shfl_xor(mx, 32));

    float mnew = fmaxf(mrun, mx);
    float scold = exp2f(mrun - mnew);

    float rsum = 0.f;
#pragma unroll
    for (int c = 0; c < 4; ++c)
#pragma unroll
      for (int j = 0; j < 4; ++j) {
        float p = exp2f(s[c][j] - mnew);
        s[c][j] = p;
        rsum += p;
      }

#pragma unroll
    for (int c = 0; c < 4; ++c) {
      ushort4 u;
      u.x = f2bf(s[c][0]); u.y = f2bf(s[c][1]);
      u.z = f2bf(s[c][2]); u.w = f2bf(s[c][3]);
      *(ushort4*)&Pme[lr * PSTR + c * 16 + lg * 4] = u;
    }

    bf16x8 v0[8];
#pragma unroll
    for (int hf = 0; hf < 8; ++hf)
      v0[hf] = *(const bf16x8*)&Vlds[(hf * 16 + lr) * VSTR + lg * 8];

    rsum += __shfl_xor(rsum, 16);
    rsum += __shfl_xor(rsum, 32);

    lrun = lrun * scold + rsum;
    mrun = mnew;
#pragma unroll
    for (int hf = 0; hf < 8; ++hf)
#pragma unroll
      for (int j = 0; j < 4; ++j) acc[hf][j] *= scold;

    bf16x8 pa0 = *(const bf16x8*)&Pme[lr * PSTR + lg * 8];
    bf16x8 pa1 = *(const bf16x8*)&Pme[lr * PSTR + 32 + lg * 8];

#pragma unroll
    for (int hf = 0; hf < 8; ++hf)
      acc[hf] = MFMA(v0[hf], pa0, acc[hf]);
#pragma unroll
    for (int hf = 0; hf < 8; ++hf) {
      bf16x8 v1 = *(const bf16x8*)&Vlds[(hf * 16 + lr) * VSTR + 32 + lg * 8];
      acc[hf] = MFMA(v1, pa1, acc[hf]);
    }
  }

  if (direct) {
    float inv = 1.0f / lrun;
    float* op = &out[(tokbase + q0 + lr) * H_DIM + lg * 4];
#pragma unroll
    for (int hf = 0; hf < 8; ++hf) {
      float4 r0 = make_float4(acc[hf][0] * inv, acc[hf][1] * inv,
                              acc[hf][2] * inv, acc[hf][3] * inv);
      *(float4*)(op + hf * 16) = r0;
    }
  } else {
    int base;
    if (qi < 48)       base = (qi - 32) * 3;
    else if (qi < 64)  base = 48 + (qi - 48) * 4;
    else if (qi < 80)  base = 112 + (qi - 64) * 5;
    else if (qi < 96)  base = 192 + (qi - 80) * 6;
    else if (qi < 112) base = 288 + (qi - 96) * 7;
    else               base = 400 + (qi - 112) * 8;
    const size_t slot = (size_t)b * SLOTS_PER_B + base + ck;
    if (lg == 0) {
      pml[slot * 32 + lr] = mrun;
      pml[slot * 32 + 16 + lr] = lrun;
    }
    ushort* ap = &pacc[slot * 2048 + (size_t)lr * 128 + lg * 4];
#pragma unroll
    for (int hf = 0; hf < 8; ++hf) {
      ushort4 u;
      u.x = f2bf(acc[hf][0]); u.y = f2bf(acc[hf][1]);
      u.z = f2bf(acc[hf][2]); u.w = f2bf(acc[hf][3]);
      *(ushort4*)(ap + hf * 16) = u;
    }
  }
}

// ---------------------------------------------------------------------------
// Kernel 2b: online merge of 3..8 partials per (b, qi) for qi >= 32.
// (unchanged)
// ---------------------------------------------------------------------------
__global__ __launch_bounds__(256) void attn_merge(const float* __restrict__ pml,
                                                  const ushort* __restrict__ pacc,
                                                  float* __restrict__ out) {
  const int bid = blockIdx.x;
  const int b = bid & 7, qi = (bid >> 3) + 32;
  int base, nch;
  if (qi < 48)       { base = (qi - 32) * 3;        nch = 3; }
  else if (qi < 64)  { base = 48 + (qi - 48) * 4;   nch = 4; }
  else if (qi < 80)  { base = 112 + (qi - 64) * 5;  nch = 5; }
  else if (qi < 96)  { base = 192 + (qi - 80) * 6;  nch = 6; }
  else if (qi < 112) { base = 288 + (qi - 96) * 7;  nch = 7; }
  else               { base = 400 + (qi - 112) * 8; nch = 8; }
  const size_t slot0 = (size_t)b * SLOTS_PER_B + base;
  const int tid = threadIdx.x;
  const int r = tid >> 4, c0 = (tid & 15) * 8;

  float mrun = -INFINITY, L = 0.f;
  float o[8];
#pragma unroll
  for (int i = 0; i < 8; ++i) o[i] = 0.f;

  for (int ck = 0; ck < nch; ++ck) {
    const size_t s = slot0 + ck;
    float m = pml[s * 32 + r];
    float l = pml[s * 32 + 16 + r];
    float mn = fmaxf(mrun, m);
    float sc = exp2f(mrun - mn);
    float w  = exp2f(m - mn);
    L = L * sc + w * l;
    const ushort* ap = &pacc[s * 2048 + (size_t)r * 128 + c0];
    ushort4 u0 = *(const ushort4*)ap;
    ushort4 u1 = *(const ushort4*)(ap + 4);
    o[0] = o[0] * sc + w * bf2f(u0.x); o[1] = o[1] * sc + w * bf2f(u0.y);
    o[2] = o[2] * sc + w * bf2f(u0.z); o[3] = o[3] * sc + w * bf2f(u0.w);
    o[4] = o[4] * sc + w * bf2f(u1.x); o[5] = o[5] * sc + w * bf2f(u1.y);
    o[6] = o[6] * sc + w * bf2f(u1.z); o[7] = o[7] * sc + w * bf2f(u1.w);
    mrun = mn;
  }
  float invL = 1.0f / L;
  float4 r0 = make_float4(o[0] * invL, o[1] * invL, o[2] * invL, o[3] * invL);
  float4 r1 = make_float4(o[4] * invL, o[5] * invL, o[6] * invL, o[7] * invL);
  float* op = &out[((size_t)b * T_LEN + qi * 16 + r) * H_DIM + c0];
  *(float4*)op = r0;
  *(float4*)(op + 4) = r1;
}

// ---------------------------------------------------------------------------
// ws layout identical to rounds 8-13 (total 30,670,848 B, proven fit):
//   [0, 786432) wt_t (dead after qkv_gemm; pml overlaps, 540,672 B)
//   qws / kws / vtws ; pacc = 8*528 slots * 2048 bf16
// ---------------------------------------------------------------------------
extern "C" void kernel_launch(void* const* d_in, const int* in_sizes, int n_in,
                              void* d_out, int out_size, void* d_ws, size_t ws_size,
                              hipStream_t stream) {
  const float* emb = (const float*)d_in[0];
  const float* Wq  = (const float*)d_in[1];
  const float* Wk  = (const float*)d_in[2];
  const float* Wv  = (const float*)d_in[3];
  float* out = (float*)d_out;

  ushort* wt   = (ushort*)d_ws;
  ushort* qws  = wt  + (size_t)N_COLS * C_DIM;
  ushort* kws  = qws + (size_t)M_ROWS * H_DIM;
  ushort* vtws = kws + (size_t)M_ROWS * H_DIM;
  ushort* pacc = vtws + (size_t)8 * H_DIM * T_LEN;
  float*  pml  = (float*)d_ws;   // overlaps dead wt region

  wt_convert<<<(N_COLS * C_DIM) / 256, 256, 0, stream>>>(Wq, Wk, Wv, wt);
  qkv_gemm<<<(M_ROWS / 64) * 2, 256, 0, stream>>>(emb, wt, qws, kws, vtws);
  attn_part<<<8 * 140, 256, 0, stream>>>(qws, kws, vtws, pml, pacc, out);
  attn_merge<<<8 * 96, 256, 0, stream>>>(pml, pacc, out);
}